// Round 3
// baseline (5436.248 us; speedup 1.0000x reference)
//
#include <hip/hip_runtime.h>

#define NFEAT 20
#define EFEAT 20
#define HID   64
#define NENV  16
#define NNODES 5000
#define NEDGES 50000
#define E2 (2*NEDGES)          // 100000 directed edges
#define ITERS 3
#define EBLK 128               // edge-kernel block size (2 waves)

__device__ __forceinline__ float fast_tanh(float x) {
    x = fminf(fmaxf(x, -15.f), 15.f);
    float e = __expf(2.f * x);
    return (e - 1.f) / (e + 1.f);
}
__device__ __forceinline__ float fast_sigmoid(float x) {
    x = fminf(fmaxf(x, -30.f), 30.f);
    return 1.f / (1.f + __expf(-x));
}

#define REP20(M) M(0) M(1) M(2) M(3) M(4) M(5) M(6) M(7) M(8) M(9) \
                 M(10) M(11) M(12) M(13) M(14) M(15) M(16) M(17) M(18) M(19)

// One thread per (env, directed edge).
// h1 lives in LDS (thread-column layout, conflict-free), so the 64-iter
// layer loops stay ROLLED — no reliance on large-loop unrolling, no
// runtime-indexed register arrays (rule #20). Outputs are 20 named scalars.
__global__ __launch_bounds__(EBLK, 1) void edge_mlp_kernel(
    const float* __restrict__ nf,      // (NENV, NNODES, NFEAT)
    const int*   __restrict__ edges,   // (2, NEDGES)
    const float* __restrict__ W1, const float* __restrict__ b1,  // (64,40),(64)
    const float* __restrict__ W2, const float* __restrict__ b2,  // (64,64),(64)
    const float* __restrict__ W3, const float* __restrict__ b3,  // (20,64),(20)
    float* __restrict__ store)         // (NENV, NNODES, EFEAT)
{
    __shared__ float h1s[HID * EBLK];          // 32 KB, column per thread
    const int tid = threadIdx.x;
    const int gid = blockIdx.x * EBLK + tid;
    const int total = NENV * E2;
    if (gid >= total) return;
    const int env = gid / E2;
    const int e   = gid - env * E2;

    int src, dst;
    if (e < NEDGES) { src = edges[e];          dst = edges[NEDGES + e]; }
    else            { int f = e - NEDGES; src = edges[NEDGES + f]; dst = edges[f]; }

    const float* __restrict__ ps = nf + ((size_t)env * NNODES + src) * NFEAT;
    const float* __restrict__ pd = nf + ((size_t)env * NNODES + dst) * NFEAT;

    float x[2 * NFEAT];
    #pragma unroll
    for (int k = 0; k < NFEAT; k++) x[k]         = ps[k];
    #pragma unroll
    for (int k = 0; k < NFEAT; k++) x[NFEAT + k] = pd[k];

    // ---- Layer 1: 40 -> 64, j rolled, h1 -> LDS ----
    for (int j = 0; j < HID; j++) {
        float acc = b1[j];
        const float* __restrict__ w = W1 + j * (2 * NFEAT);
        #pragma unroll
        for (int k = 0; k < 2 * NFEAT; k++)
            acc = fmaf(x[k], w[k], acc);
        h1s[j * EBLK + tid] = fast_tanh(acc);
    }
    // no __syncthreads(): each thread touches only its own LDS column

    // ---- Layers 2+3 fused: 64 -> 64 -> 20 ----
#define DECL_OUT(m) float o##m = b3[m];
    REP20(DECL_OUT)
#undef DECL_OUT

    for (int jc = 0; jc < HID / 8; jc++) {     // rolled: 8 chunks
        const float* __restrict__ w2 = W2 + (jc * 8) * HID;
        float a0 = b2[jc*8+0], a1 = b2[jc*8+1], a2 = b2[jc*8+2], a3 = b2[jc*8+3];
        float a4 = b2[jc*8+4], a5 = b2[jc*8+5], a6 = b2[jc*8+6], a7 = b2[jc*8+7];
        #pragma unroll 8
        for (int k = 0; k < HID; k++) {
            float hk = h1s[k * EBLK + tid];
            a0 = fmaf(hk, w2[0*HID + k], a0);
            a1 = fmaf(hk, w2[1*HID + k], a1);
            a2 = fmaf(hk, w2[2*HID + k], a2);
            a3 = fmaf(hk, w2[3*HID + k], a3);
            a4 = fmaf(hk, w2[4*HID + k], a4);
            a5 = fmaf(hk, w2[5*HID + k], a5);
            a6 = fmaf(hk, w2[6*HID + k], a6);
            a7 = fmaf(hk, w2[7*HID + k], a7);
        }
        a0 = fast_tanh(a0); a1 = fast_tanh(a1); a2 = fast_tanh(a2); a3 = fast_tanh(a3);
        a4 = fast_tanh(a4); a5 = fast_tanh(a5); a6 = fast_tanh(a6); a7 = fast_tanh(a7);
#define ACC_OUT(m) { const float* __restrict__ w3r = W3 + (m) * HID + jc * 8;           \
        o##m = fmaf(a0, w3r[0], o##m); o##m = fmaf(a1, w3r[1], o##m);                   \
        o##m = fmaf(a2, w3r[2], o##m); o##m = fmaf(a3, w3r[3], o##m);                   \
        o##m = fmaf(a4, w3r[4], o##m); o##m = fmaf(a5, w3r[5], o##m);                   \
        o##m = fmaf(a6, w3r[6], o##m); o##m = fmaf(a7, w3r[7], o##m); }
        REP20(ACC_OUT)
#undef ACC_OUT
    }

    float* sp = store + ((size_t)env * NNODES + src) * EFEAT;
#define ATOM(m) atomicAdd(&sp[m], o##m);
    REP20(ATOM)
#undef ATOM
}

// One thread per (env, node): GRU single step, in-place on nf.
// t rolled; named scalar accumulators; sv/hv only touched by 20-iter
// single-instruction unrolled loops.
__global__ __launch_bounds__(256) void gru_kernel(
    const float* __restrict__ store,   // (NENV, NNODES, EFEAT)
    const float* __restrict__ Wih, const float* __restrict__ bih,  // (60,20),(60)
    const float* __restrict__ Whh, const float* __restrict__ bhh,  // (60,20),(60)
    float* __restrict__ nf)            // (NENV, NNODES, NFEAT) in/out
{
    int gid = blockIdx.x * blockDim.x + threadIdx.x;
    const int total = NENV * NNODES;
    if (gid >= total) return;

    const float* s = store + (size_t)gid * EFEAT;
    float*       h = nf    + (size_t)gid * NFEAT;

    float sv[EFEAT], hv[NFEAT];
    #pragma unroll
    for (int k = 0; k < EFEAT; k++) sv[k] = s[k];
    #pragma unroll
    for (int k = 0; k < NFEAT; k++) hv[k] = h[k];

    for (int t = 0; t < NFEAT; t++) {   // rolled: 20 iterations
        float ir = bih[t],            hr = bhh[t];
        float iz = bih[NFEAT + t],    hz = bhh[NFEAT + t];
        float in_ = bih[2*NFEAT + t], hn = bhh[2*NFEAT + t];
        const float* wr = Wih + t * EFEAT;
        const float* wz = Wih + (NFEAT + t) * EFEAT;
        const float* wn = Wih + (2*NFEAT + t) * EFEAT;
        #pragma unroll
        for (int k = 0; k < EFEAT; k++) {
            ir  = fmaf(sv[k], wr[k], ir);
            iz  = fmaf(sv[k], wz[k], iz);
            in_ = fmaf(sv[k], wn[k], in_);
        }
        const float* vr = Whh + t * NFEAT;
        const float* vz = Whh + (NFEAT + t) * NFEAT;
        const float* vn = Whh + (2*NFEAT + t) * NFEAT;
        #pragma unroll
        for (int k = 0; k < NFEAT; k++) {
            hr = fmaf(hv[k], vr[k], hr);
            hz = fmaf(hv[k], vz[k], hz);
            hn = fmaf(hv[k], vn[k], hn);
        }
        float r = fast_sigmoid(ir + hr);
        float z = fast_sigmoid(iz + hz);
        float n = fast_tanh(in_ + r * hn);
        h[t] = (1.f - z) * n + z * hv[t];
    }
}

extern "C" void kernel_launch(void* const* d_in, const int* in_sizes, int n_in,
                              void* d_out, int out_size, void* d_ws, size_t ws_size,
                              hipStream_t stream) {
    const float* nf_in  = (const float*)d_in[0];
    const int*   edges  = (const int*)d_in[1];
    const float* W1 = (const float*)d_in[2];
    const float* b1 = (const float*)d_in[3];
    const float* W2 = (const float*)d_in[4];
    const float* b2 = (const float*)d_in[5];
    const float* W3 = (const float*)d_in[6];
    const float* b3 = (const float*)d_in[7];
    const float* Wih = (const float*)d_in[8];
    const float* Whh = (const float*)d_in[9];
    const float* bih = (const float*)d_in[10];
    const float* bhh = (const float*)d_in[11];

    float* nf    = (float*)d_out;                       // working node features
    float* store = (float*)d_ws;                        // (NENV,NNODES,EFEAT)
    const size_t nf_bytes    = (size_t)NENV * NNODES * NFEAT * sizeof(float);
    const size_t store_bytes = (size_t)NENV * NNODES * EFEAT * sizeof(float);

    hipMemcpyAsync(nf, nf_in, nf_bytes, hipMemcpyDeviceToDevice, stream);

    const int edge_total = NENV * E2;
    const int node_total = NENV * NNODES;
    dim3 grid_e((edge_total + EBLK - 1) / EBLK);
    dim3 grid_n((node_total + 255) / 256);

    for (int it = 0; it < ITERS; it++) {
        hipMemsetAsync(store, 0, store_bytes, stream);
        edge_mlp_kernel<<<grid_e, dim3(EBLK), 0, stream>>>(nf, edges, W1, b1, W2, b2, W3, b3, store);
        gru_kernel<<<grid_n, dim3(256), 0, stream>>>(store, Wih, bih, Whh, bhh, nf);
    }
}

// Round 5
// 1648.956 us; speedup vs baseline: 3.2968x; 3.2968x over previous
//
#include <hip/hip_runtime.h>

#define NFEAT 20
#define EFEAT 20
#define HID   64
#define NENV  16
#define NNODES 5000
#define NEDGES 50000
#define E2 (2*NEDGES)          // 100000 directed edges
#define ITERS 3
#define ROWS 128               // edge rows per block (2 waves x 64 rows)

typedef __attribute__((ext_vector_type(8))) short bf16x8;
typedef __attribute__((ext_vector_type(4))) float f32x4;

__device__ __forceinline__ ushort f2b(float f) {   // f32 -> bf16 RNE
    unsigned u = __float_as_uint(f);
    u = (u + 0x7fffu + ((u >> 16) & 1u)) >> 16;
    return (ushort)u;
}
__device__ __forceinline__ float b2f(ushort h) {
    return __uint_as_float(((unsigned)h) << 16);
}
__device__ __forceinline__ float fast_tanh(float x) {
    x = fminf(fmaxf(x, -15.f), 15.f);
    float e = __expf(2.f * x);
    return (e - 1.f) / (e + 1.f);
}
__device__ __forceinline__ float fast_sigmoid(float x) {
    x = fminf(fmaxf(x, -30.f), 30.f);
    return 1.f / (1.f + __expf(-x));
}
// split f32 -> (hi, lo) bf16 pair: v ~= hi + lo, |err| ~ 2^-18 |v|
__device__ __forceinline__ void packhl(float4 a, float4 b, bf16x8& hi, bf16x8& lo) {
#define P(i, val) { ushort h_ = f2b(val); hi[i] = (short)h_; lo[i] = (short)f2b((val) - b2f(h_)); }
    P(0, a.x) P(1, a.y) P(2, a.z) P(3, a.w)
    P(4, b.x) P(5, b.y) P(6, b.z) P(7, b.w)
#undef P
}

// Convert weights once to split-bf16, B^T layout [out][k], K padded to 64.
__global__ void prep_weights(const float* __restrict__ W1, const float* __restrict__ W2,
                             const float* __restrict__ W3,
                             ushort* __restrict__ W1h, ushort* __restrict__ W1l,
                             ushort* __restrict__ W2h, ushort* __restrict__ W2l,
                             ushort* __restrict__ W3h, ushort* __restrict__ W3l) {
    int t = threadIdx.x;
    for (int i = t; i < 64 * 64; i += 256) {           // W1 [64][64], k<40 valid
        int n = i >> 6, k = i & 63;
        float v = (k < 2 * NFEAT) ? W1[n * (2 * NFEAT) + k] : 0.f;
        ushort h = f2b(v);
        W1h[i] = h; W1l[i] = f2b(v - b2f(h));
    }
    for (int i = t; i < 64 * 64; i += 256) {           // W2 [64][64]
        float v = W2[i];
        ushort h = f2b(v);
        W2h[i] = h; W2l[i] = f2b(v - b2f(h));
    }
    for (int i = t; i < 32 * 64; i += 256) {           // W3 [32][64], n<20 valid
        int n = i >> 6, k = i & 63;
        float v = (n < EFEAT) ? W3[n * HID + k] : 0.f;
        ushort h = f2b(v);
        W3h[i] = h; W3l[i] = f2b(v - b2f(h));
    }
}

// 128 edge-rows per block, 2 waves, each wave owns 64 rows (wave-local LDS
// slices -> NO barriers). Split-bf16 compensated MFMA:
//   acc = Ahi*Bhi + Alo*Bhi + Ahi*Blo   (per K-tile)
// All activations stored as hi/lo bf16 plane pairs in LDS, XOR-swizzled
// (granule ^= row&7) to avoid the stride-128B bank conflict.
__global__ __launch_bounds__(ROWS) void edge_mlp_mfma(
    const float* __restrict__ nf,        // (NENV, NNODES, NFEAT) f32
    const int*   __restrict__ edges,     // flat (2*NEDGES)
    const ushort* __restrict__ W1h, const ushort* __restrict__ W1l,
    const ushort* __restrict__ W2h, const ushort* __restrict__ W2l,
    const ushort* __restrict__ W3h, const ushort* __restrict__ W3l,
    const float* __restrict__ b1, const float* __restrict__ b2,
    const float* __restrict__ b3,
    float* __restrict__ store)           // (NENV, NNODES, EFEAT) f32
{
    __shared__ bf16x8 Xhi[ROWS * 8], Xlo[ROWS * 8];   // X, later H2 (16 KB each)
    __shared__ bf16x8 Hhi[ROWS * 8], Hlo[ROWS * 8];   // H1
    ushort* Xhi16 = (ushort*)Xhi; ushort* Xlo16 = (ushort*)Xlo;
    ushort* Hhi16 = (ushort*)Hhi; ushort* Hlo16 = (ushort*)Hlo;

    const int tid = threadIdx.x;

    // ---- gather: one thread = one edge row; split X into hi/lo planes ----
    {
        int gid = blockIdx.x * ROWS + tid;
        int env = gid / E2;
        int e   = gid - env * E2;
        int src = edges[e];                                   // src of either direction
        int dst = (e < NEDGES) ? edges[NEDGES + e] : edges[e - NEDGES];
        const float4* ps = (const float4*)(nf + ((size_t)env * NNODES + src) * NFEAT);
        const float4* pd = (const float4*)(nf + ((size_t)env * NNODES + dst) * NFEAT);
        float4 s0 = ps[0], s1 = ps[1], s2 = ps[2], s3 = ps[3], s4 = ps[4];
        float4 d0 = pd[0], d1 = pd[1], d2 = pd[2], d3 = pd[3], d4 = pd[4];
        int rb = tid * 8, sw = tid & 7;
        bf16x8 hi, lo;
        packhl(s0, s1, hi, lo); Xhi[rb + (0 ^ sw)] = hi; Xlo[rb + (0 ^ sw)] = lo;
        packhl(s2, s3, hi, lo); Xhi[rb + (1 ^ sw)] = hi; Xlo[rb + (1 ^ sw)] = lo;
        packhl(s4, d0, hi, lo); Xhi[rb + (2 ^ sw)] = hi; Xlo[rb + (2 ^ sw)] = lo;
        packhl(d1, d2, hi, lo); Xhi[rb + (3 ^ sw)] = hi; Xlo[rb + (3 ^ sw)] = lo;
        packhl(d3, d4, hi, lo); Xhi[rb + (4 ^ sw)] = hi; Xlo[rb + (4 ^ sw)] = lo;
        bf16x8 z = {0,0,0,0,0,0,0,0};
        Xhi[rb + (5 ^ sw)] = z; Xlo[rb + (5 ^ sw)] = z;
        Xhi[rb + (6 ^ sw)] = z; Xlo[rb + (6 ^ sw)] = z;
        Xhi[rb + (7 ^ sw)] = z; Xlo[rb + (7 ^ sw)] = z;
    }

    const int wave = tid >> 6;
    const int lane = tid & 63;
    const int lr   = lane & 15;      // A-row-in-tile / B-col / C-col
    const int kg   = lane >> 4;      // 0..3: k-group for A/B, row-group for C
    const int m0   = wave * 64;
    const f32x4 zero4 = {0.f, 0.f, 0.f, 0.f};

#define MFMA6(acc, a0h, a0l, a1h, a1l, bh0, bl0, bh1, bl1)                          \
    acc = __builtin_amdgcn_mfma_f32_16x16x32_bf16(a0h, bh0, acc, 0, 0, 0);          \
    acc = __builtin_amdgcn_mfma_f32_16x16x32_bf16(a0l, bh0, acc, 0, 0, 0);          \
    acc = __builtin_amdgcn_mfma_f32_16x16x32_bf16(a0h, bl0, acc, 0, 0, 0);          \
    acc = __builtin_amdgcn_mfma_f32_16x16x32_bf16(a1h, bh1, acc, 0, 0, 0);          \
    acc = __builtin_amdgcn_mfma_f32_16x16x32_bf16(a1l, bh1, acc, 0, 0, 0);          \
    acc = __builtin_amdgcn_mfma_f32_16x16x32_bf16(a1h, bl1, acc, 0, 0, 0);

    // ---- GEMM1: X @ W1^T -> +b1, tanh -> H1 (split) ----
    {
        bf16x8 bh[4][2], bl[4][2];
        #pragma unroll
        for (int n = 0; n < 4; n++)
            #pragma unroll
            for (int kt = 0; kt < 2; kt++) {
                bh[n][kt] = *(const bf16x8*)(W1h + (n * 16 + lr) * 64 + kt * 32 + kg * 8);
                bl[n][kt] = *(const bf16x8*)(W1l + (n * 16 + lr) * 64 + kt * 32 + kg * 8);
            }
        float bb[4];
        #pragma unroll
        for (int n = 0; n < 4; n++) bb[n] = b1[n * 16 + lr];
        for (int m = 0; m < 4; m++) {
            int arow = m0 + m * 16 + lr, sw = arow & 7;
            bf16x8 a0h = Xhi[arow * 8 + (kg ^ sw)];
            bf16x8 a0l = Xlo[arow * 8 + (kg ^ sw)];
            bf16x8 a1h = Xhi[arow * 8 + ((4 + kg) ^ sw)];
            bf16x8 a1l = Xlo[arow * 8 + ((4 + kg) ^ sw)];
            f32x4 acc[4];
            #pragma unroll
            for (int n = 0; n < 4; n++) {
                acc[n] = zero4;
                MFMA6(acc[n], a0h, a0l, a1h, a1l, bh[n][0], bl[n][0], bh[n][1], bl[n][1])
            }
            #pragma unroll
            for (int n = 0; n < 4; n++) {
                int col = n * 16 + lr;
                #pragma unroll
                for (int r = 0; r < 4; r++) {
                    int row = m0 + m * 16 + kg * 4 + r;
                    float t = fast_tanh(acc[n][r] + bb[n]);
                    ushort h = f2b(t);
                    int idx = row * 64 + (col ^ ((row & 7) << 3));
                    Hhi16[idx] = h;
                    Hlo16[idx] = f2b(t - b2f(h));
                }
            }
        }
    }

    // ---- GEMM2: H1 @ W2^T -> +b2, tanh -> H2 (into X planes) ----
    {
        bf16x8 bh[4][2], bl[4][2];
        #pragma unroll
        for (int n = 0; n < 4; n++)
            #pragma unroll
            for (int kt = 0; kt < 2; kt++) {
                bh[n][kt] = *(const bf16x8*)(W2h + (n * 16 + lr) * 64 + kt * 32 + kg * 8);
                bl[n][kt] = *(const bf16x8*)(W2l + (n * 16 + lr) * 64 + kt * 32 + kg * 8);
            }
        float bb[4];
        #pragma unroll
        for (int n = 0; n < 4; n++) bb[n] = b2[n * 16 + lr];
        for (int m = 0; m < 4; m++) {
            int arow = m0 + m * 16 + lr, sw = arow & 7;
            bf16x8 a0h = Hhi[arow * 8 + (kg ^ sw)];
            bf16x8 a0l = Hlo[arow * 8 + (kg ^ sw)];
            bf16x8 a1h = Hhi[arow * 8 + ((4 + kg) ^ sw)];
            bf16x8 a1l = Hlo[arow * 8 + ((4 + kg) ^ sw)];
            f32x4 acc[4];
            #pragma unroll
            for (int n = 0; n < 4; n++) {
                acc[n] = zero4;
                MFMA6(acc[n], a0h, a0l, a1h, a1l, bh[n][0], bl[n][0], bh[n][1], bl[n][1])
            }
            #pragma unroll
            for (int n = 0; n < 4; n++) {
                int col = n * 16 + lr;
                #pragma unroll
                for (int r = 0; r < 4; r++) {
                    int row = m0 + m * 16 + kg * 4 + r;
                    float t = fast_tanh(acc[n][r] + bb[n]);
                    ushort h = f2b(t);
                    int idx = row * 64 + (col ^ ((row & 7) << 3));
                    Xhi16[idx] = h;
                    Xlo16[idx] = f2b(t - b2f(h));
                }
            }
        }
    }

    // ---- GEMM3: H2 @ W3^T -> +b3, atomic scatter to store[env][src] ----
    {
        bf16x8 bh[2][2], bl[2][2];
        #pragma unroll
        for (int n = 0; n < 2; n++)
            #pragma unroll
            for (int kt = 0; kt < 2; kt++) {
                bh[n][kt] = *(const bf16x8*)(W3h + (n * 16 + lr) * 64 + kt * 32 + kg * 8);
                bl[n][kt] = *(const bf16x8*)(W3l + (n * 16 + lr) * 64 + kt * 32 + kg * 8);
            }
        float bb0 = b3[lr];                        // cols 0..15
        float bb1 = (lr < 4) ? b3[16 + lr] : 0.f;  // cols 16..19
        for (int m = 0; m < 4; m++) {
            int arow = m0 + m * 16 + lr, sw = arow & 7;
            bf16x8 a0h = Xhi[arow * 8 + (kg ^ sw)];
            bf16x8 a0l = Xlo[arow * 8 + (kg ^ sw)];
            bf16x8 a1h = Xhi[arow * 8 + ((4 + kg) ^ sw)];
            bf16x8 a1l = Xlo[arow * 8 + ((4 + kg) ^ sw)];
            f32x4 acc0 = zero4, acc1 = zero4;
            MFMA6(acc0, a0h, a0l, a1h, a1l, bh[0][0], bl[0][0], bh[0][1], bl[0][1])
            MFMA6(acc1, a0h, a0l, a1h, a1l, bh[1][0], bl[1][0], bh[1][1], bl[1][1])
            #pragma unroll
            for (int r = 0; r < 4; r++) {
                int row = m0 + m * 16 + kg * 4 + r;
                int gid = blockIdx.x * ROWS + row;
                int env = gid / E2;
                int e   = gid - env * E2;
                int src = edges[e];                // src is edges[e] for BOTH directions
                float* sp = store + ((size_t)env * NNODES + src) * EFEAT;
                atomicAdd(sp + lr, acc0[r] + bb0);
                if (lr < 4) atomicAdd(sp + 16 + lr, acc1[r] + bb1);
            }
        }
    }
#undef MFMA6
}

// One thread per (env, node): GRU single step, in-place on nf (f32).
__global__ __launch_bounds__(256) void gru_kernel(
    const float* __restrict__ store,
    const float* __restrict__ Wih, const float* __restrict__ bih,
    const float* __restrict__ Whh, const float* __restrict__ bhh,
    float* __restrict__ nf)
{
    int gid = blockIdx.x * blockDim.x + threadIdx.x;
    const int total = NENV * NNODES;
    if (gid >= total) return;

    const float* s = store + (size_t)gid * EFEAT;
    float*       h = nf    + (size_t)gid * NFEAT;

    float sv[EFEAT], hv[NFEAT];
    #pragma unroll
    for (int k = 0; k < EFEAT; k++) sv[k] = s[k];
    #pragma unroll
    for (int k = 0; k < NFEAT; k++) hv[k] = h[k];

    for (int t = 0; t < NFEAT; t++) {
        float ir = bih[t],            hr = bhh[t];
        float iz = bih[NFEAT + t],    hz = bhh[NFEAT + t];
        float in_ = bih[2*NFEAT + t], hn = bhh[2*NFEAT + t];
        const float* wr = Wih + t * EFEAT;
        const float* wz = Wih + (NFEAT + t) * EFEAT;
        const float* wn = Wih + (2*NFEAT + t) * EFEAT;
        #pragma unroll
        for (int k = 0; k < EFEAT; k++) {
            ir  = fmaf(sv[k], wr[k], ir);
            iz  = fmaf(sv[k], wz[k], iz);
            in_ = fmaf(sv[k], wn[k], in_);
        }
        const float* vr = Whh + t * NFEAT;
        const float* vz = Whh + (NFEAT + t) * NFEAT;
        const float* vn = Whh + (2*NFEAT + t) * NFEAT;
        #pragma unroll
        for (int k = 0; k < NFEAT; k++) {
            hr = fmaf(hv[k], vr[k], hr);
            hz = fmaf(hv[k], vz[k], hz);
            hn = fmaf(hv[k], vn[k], hn);
        }
        float r = fast_sigmoid(ir + hr);
        float z = fast_sigmoid(iz + hz);
        float n = fast_tanh(in_ + r * hn);
        h[t] = (1.f - z) * n + z * hv[t];
    }
}

extern "C" void kernel_launch(void* const* d_in, const int* in_sizes, int n_in,
                              void* d_out, int out_size, void* d_ws, size_t ws_size,
                              hipStream_t stream) {
    const float* nf_in = (const float*)d_in[0];
    const int*   edges = (const int*)d_in[1];
    const float* W1 = (const float*)d_in[2];
    const float* b1 = (const float*)d_in[3];
    const float* W2 = (const float*)d_in[4];
    const float* b2 = (const float*)d_in[5];
    const float* W3 = (const float*)d_in[6];
    const float* b3 = (const float*)d_in[7];
    const float* Wih = (const float*)d_in[8];
    const float* Whh = (const float*)d_in[9];
    const float* bih = (const float*)d_in[10];
    const float* bhh = (const float*)d_in[11];

    float* nf    = (float*)d_out;
    float* store = (float*)d_ws;
    const size_t nf_bytes    = (size_t)NENV * NNODES * NFEAT * sizeof(float);
    const size_t store_bytes = (size_t)NENV * NNODES * EFEAT * sizeof(float);
    ushort* W1h = (ushort*)((char*)d_ws + store_bytes);
    ushort* W1l = W1h + 64 * 64;
    ushort* W2h = W1l + 64 * 64;
    ushort* W2l = W2h + 64 * 64;
    ushort* W3h = W2l + 64 * 64;
    ushort* W3l = W3h + 32 * 64;

    prep_weights<<<1, 256, 0, stream>>>(W1, W2, W3, W1h, W1l, W2h, W2l, W3h, W3l);
    hipMemcpyAsync(nf, nf_in, nf_bytes, hipMemcpyDeviceToDevice, stream);

    const int edge_blocks = (NENV * E2) / ROWS;           // 12500, exact
    const int node_total  = NENV * NNODES;
    dim3 grid_n((node_total + 255) / 256);

    for (int it = 0; it < ITERS; it++) {
        hipMemsetAsync(store, 0, store_bytes, stream);
        edge_mlp_mfma<<<edge_blocks, ROWS, 0, stream>>>(nf, edges,
                                                        W1h, W1l, W2h, W2l, W3h, W3l,
                                                        b1, b2, b3, store);
        gru_kernel<<<grid_n, 256, 0, stream>>>(store, Wih, bih, Whh, bhh, nf);
    }
}

// Round 6
// 1099.254 us; speedup vs baseline: 4.9454x; 1.5001x over previous
//
#include <hip/hip_runtime.h>

#define NFEAT 20
#define EFEAT 20
#define HID   64
#define NENV  16
#define NNODES 5000
#define NEDGES 50000
#define E2 (2*NEDGES)          // 100000 directed edges
#define ITERS 3
#define ROWS 128               // edge rows per block (2 waves x 64 rows)

typedef __attribute__((ext_vector_type(8))) short bf16x8;
typedef __attribute__((ext_vector_type(4))) float f32x4;

__device__ __forceinline__ ushort f2b(float f) {   // f32 -> bf16 RNE
    unsigned u = __float_as_uint(f);
    u = (u + 0x7fffu + ((u >> 16) & 1u)) >> 16;
    return (ushort)u;
}
__device__ __forceinline__ float b2f(ushort h) {
    return __uint_as_float(((unsigned)h) << 16);
}
__device__ __forceinline__ float fast_tanh(float x) {
    x = fminf(fmaxf(x, -15.f), 15.f);
    float e = __expf(2.f * x);
    return (e - 1.f) / (e + 1.f);
}
__device__ __forceinline__ float fast_sigmoid(float x) {
    x = fminf(fmaxf(x, -30.f), 30.f);
    return 1.f / (1.f + __expf(-x));
}
// split f32 -> (hi, lo) bf16 pair: v ~= hi + lo, |err| ~ 2^-18 |v|
__device__ __forceinline__ void packhl(float4 a, float4 b, bf16x8& hi, bf16x8& lo) {
#define P(i, val) { ushort h_ = f2b(val); hi[i] = (short)h_; lo[i] = (short)f2b((val) - b2f(h_)); }
    P(0, a.x) P(1, a.y) P(2, a.z) P(3, a.w)
    P(4, b.x) P(5, b.y) P(6, b.z) P(7, b.w)
#undef P
}

// Convert weights once to split-bf16, B^T layout [out][k], K padded to 64.
__global__ void prep_weights(const float* __restrict__ W1, const float* __restrict__ W2,
                             const float* __restrict__ W3,
                             ushort* __restrict__ W1h, ushort* __restrict__ W1l,
                             ushort* __restrict__ W2h, ushort* __restrict__ W2l,
                             ushort* __restrict__ W3h, ushort* __restrict__ W3l) {
    int t = threadIdx.x;
    for (int i = t; i < 64 * 64; i += 256) {           // W1 [64][64], k<40 valid
        int n = i >> 6, k = i & 63;
        float v = (k < 2 * NFEAT) ? W1[n * (2 * NFEAT) + k] : 0.f;
        ushort h = f2b(v);
        W1h[i] = h; W1l[i] = f2b(v - b2f(h));
    }
    for (int i = t; i < 64 * 64; i += 256) {           // W2 [64][64]
        float v = W2[i];
        ushort h = f2b(v);
        W2h[i] = h; W2l[i] = f2b(v - b2f(h));
    }
    for (int i = t; i < 32 * 64; i += 256) {           // W3 [32][64], n<20 valid
        int n = i >> 6, k = i & 63;
        float v = (n < EFEAT) ? W3[n * HID + k] : 0.f;
        ushort h = f2b(v);
        W3h[i] = h; W3l[i] = f2b(v - b2f(h));
    }
}

// 128 edge-rows per block, 2 waves, each wave owns 64 rows (wave-local LDS
// slices -> NO barriers). Split-bf16 compensated MFMA:
//   acc = Ahi*Bhi + Alo*Bhi + Ahi*Blo   (per K-tile)
// SINGLE activation buffer pair (hi/lo): X -> (in-place, per 16-row tile)
// H1 -> H2. Safe because each GEMM loads its A-tile to registers before the
// epilogue overwrites the same 16 rows. 32 KB LDS -> 5 blocks/CU.
__global__ __launch_bounds__(ROWS) void edge_mlp_mfma(
    const float* __restrict__ nf,        // (NENV, NNODES, NFEAT) f32
    const int*   __restrict__ edges,     // flat (2*NEDGES)
    const ushort* __restrict__ W1h, const ushort* __restrict__ W1l,
    const ushort* __restrict__ W2h, const ushort* __restrict__ W2l,
    const ushort* __restrict__ W3h, const ushort* __restrict__ W3l,
    const float* __restrict__ b1, const float* __restrict__ b2,
    const float* __restrict__ b3,
    float* __restrict__ store)           // (NENV, NNODES, EFEAT) f32
{
    __shared__ bf16x8 Ahi[ROWS * 8], Alo[ROWS * 8];   // 16 KB each
    ushort* Ahi16 = (ushort*)Ahi; ushort* Alo16 = (ushort*)Alo;

    const int tid = threadIdx.x;

    // ---- gather: one thread = one edge row; split X into hi/lo planes ----
    {
        int gid = blockIdx.x * ROWS + tid;
        int env = gid / E2;
        int e   = gid - env * E2;
        int src = edges[e];                                   // src of either direction
        int dst = (e < NEDGES) ? edges[NEDGES + e] : edges[e - NEDGES];
        const float4* ps = (const float4*)(nf + ((size_t)env * NNODES + src) * NFEAT);
        const float4* pd = (const float4*)(nf + ((size_t)env * NNODES + dst) * NFEAT);
        float4 s0 = ps[0], s1 = ps[1], s2 = ps[2], s3 = ps[3], s4 = ps[4];
        float4 d0 = pd[0], d1 = pd[1], d2 = pd[2], d3 = pd[3], d4 = pd[4];
        int rb = tid * 8, sw = tid & 7;
        bf16x8 hi, lo;
        packhl(s0, s1, hi, lo); Ahi[rb + (0 ^ sw)] = hi; Alo[rb + (0 ^ sw)] = lo;
        packhl(s2, s3, hi, lo); Ahi[rb + (1 ^ sw)] = hi; Alo[rb + (1 ^ sw)] = lo;
        packhl(s4, d0, hi, lo); Ahi[rb + (2 ^ sw)] = hi; Alo[rb + (2 ^ sw)] = lo;
        packhl(d1, d2, hi, lo); Ahi[rb + (3 ^ sw)] = hi; Alo[rb + (3 ^ sw)] = lo;
        packhl(d3, d4, hi, lo); Ahi[rb + (4 ^ sw)] = hi; Alo[rb + (4 ^ sw)] = lo;
        bf16x8 z = {0,0,0,0,0,0,0,0};
        Ahi[rb + (5 ^ sw)] = z; Alo[rb + (5 ^ sw)] = z;
        Ahi[rb + (6 ^ sw)] = z; Alo[rb + (6 ^ sw)] = z;
        Ahi[rb + (7 ^ sw)] = z; Alo[rb + (7 ^ sw)] = z;
    }

    const int wave = tid >> 6;
    const int lane = tid & 63;
    const int lr   = lane & 15;      // A-row-in-tile / B-col / C-col
    const int kg   = lane >> 4;      // 0..3: k-group for A/B, row-group for C
    const int m0   = wave * 64;
    const f32x4 zero4 = {0.f, 0.f, 0.f, 0.f};

#define MFMA6(acc, a0h, a0l, a1h, a1l, bh0, bl0, bh1, bl1)                          \
    acc = __builtin_amdgcn_mfma_f32_16x16x32_bf16(a0h, bh0, acc, 0, 0, 0);          \
    acc = __builtin_amdgcn_mfma_f32_16x16x32_bf16(a0l, bh0, acc, 0, 0, 0);          \
    acc = __builtin_amdgcn_mfma_f32_16x16x32_bf16(a0h, bl0, acc, 0, 0, 0);          \
    acc = __builtin_amdgcn_mfma_f32_16x16x32_bf16(a1h, bh1, acc, 0, 0, 0);          \
    acc = __builtin_amdgcn_mfma_f32_16x16x32_bf16(a1l, bh1, acc, 0, 0, 0);          \
    acc = __builtin_amdgcn_mfma_f32_16x16x32_bf16(a1h, bl1, acc, 0, 0, 0);

    // ---- GEMM1: X @ W1^T -> +b1, tanh -> H1 (in place over X) ----
    {
        bf16x8 bh[4][2], bl[4][2];
        #pragma unroll
        for (int n = 0; n < 4; n++)
            #pragma unroll
            for (int kt = 0; kt < 2; kt++) {
                bh[n][kt] = *(const bf16x8*)(W1h + (n * 16 + lr) * 64 + kt * 32 + kg * 8);
                bl[n][kt] = *(const bf16x8*)(W1l + (n * 16 + lr) * 64 + kt * 32 + kg * 8);
            }
        float bb[4];
        #pragma unroll
        for (int n = 0; n < 4; n++) bb[n] = b1[n * 16 + lr];
        for (int m = 0; m < 4; m++) {
            int arow = m0 + m * 16 + lr, sw = arow & 7;
            bf16x8 a0h = Ahi[arow * 8 + (kg ^ sw)];
            bf16x8 a0l = Alo[arow * 8 + (kg ^ sw)];
            bf16x8 a1h = Ahi[arow * 8 + ((4 + kg) ^ sw)];
            bf16x8 a1l = Alo[arow * 8 + ((4 + kg) ^ sw)];
            f32x4 acc[4];
            #pragma unroll
            for (int n = 0; n < 4; n++) {
                acc[n] = zero4;
                MFMA6(acc[n], a0h, a0l, a1h, a1l, bh[n][0], bl[n][0], bh[n][1], bl[n][1])
            }
            #pragma unroll
            for (int n = 0; n < 4; n++) {
                int col = n * 16 + lr;
                #pragma unroll
                for (int r = 0; r < 4; r++) {
                    int row = m0 + m * 16 + kg * 4 + r;
                    float t = fast_tanh(acc[n][r] + bb[n]);
                    ushort h = f2b(t);
                    int idx = row * 64 + (col ^ ((row & 7) << 3));
                    Ahi16[idx] = h;
                    Alo16[idx] = f2b(t - b2f(h));
                }
            }
        }
    }

    // ---- GEMM2: H1 @ W2^T -> +b2, tanh -> H2 (in place over H1) ----
    {
        bf16x8 bh[4][2], bl[4][2];
        #pragma unroll
        for (int n = 0; n < 4; n++)
            #pragma unroll
            for (int kt = 0; kt < 2; kt++) {
                bh[n][kt] = *(const bf16x8*)(W2h + (n * 16 + lr) * 64 + kt * 32 + kg * 8);
                bl[n][kt] = *(const bf16x8*)(W2l + (n * 16 + lr) * 64 + kt * 32 + kg * 8);
            }
        float bb[4];
        #pragma unroll
        for (int n = 0; n < 4; n++) bb[n] = b2[n * 16 + lr];
        for (int m = 0; m < 4; m++) {
            int arow = m0 + m * 16 + lr, sw = arow & 7;
            bf16x8 a0h = Ahi[arow * 8 + (kg ^ sw)];
            bf16x8 a0l = Alo[arow * 8 + (kg ^ sw)];
            bf16x8 a1h = Ahi[arow * 8 + ((4 + kg) ^ sw)];
            bf16x8 a1l = Alo[arow * 8 + ((4 + kg) ^ sw)];
            f32x4 acc[4];
            #pragma unroll
            for (int n = 0; n < 4; n++) {
                acc[n] = zero4;
                MFMA6(acc[n], a0h, a0l, a1h, a1l, bh[n][0], bl[n][0], bh[n][1], bl[n][1])
            }
            #pragma unroll
            for (int n = 0; n < 4; n++) {
                int col = n * 16 + lr;
                #pragma unroll
                for (int r = 0; r < 4; r++) {
                    int row = m0 + m * 16 + kg * 4 + r;
                    float t = fast_tanh(acc[n][r] + bb[n]);
                    ushort h = f2b(t);
                    int idx = row * 64 + (col ^ ((row & 7) << 3));
                    Ahi16[idx] = h;
                    Alo16[idx] = f2b(t - b2f(h));
                }
            }
        }
    }

    // ---- GEMM3: H2 @ W3^T -> +b3, atomic scatter to store[env][src] ----
    {
        bf16x8 bh[2][2], bl[2][2];
        #pragma unroll
        for (int n = 0; n < 2; n++)
            #pragma unroll
            for (int kt = 0; kt < 2; kt++) {
                bh[n][kt] = *(const bf16x8*)(W3h + (n * 16 + lr) * 64 + kt * 32 + kg * 8);
                bl[n][kt] = *(const bf16x8*)(W3l + (n * 16 + lr) * 64 + kt * 32 + kg * 8);
            }
        float bb0 = b3[lr];                        // cols 0..15
        float bb1 = (lr < 4) ? b3[16 + lr] : 0.f;  // cols 16..19
        for (int m = 0; m < 4; m++) {
            int arow = m0 + m * 16 + lr, sw = arow & 7;
            bf16x8 a0h = Ahi[arow * 8 + (kg ^ sw)];
            bf16x8 a0l = Alo[arow * 8 + (kg ^ sw)];
            bf16x8 a1h = Ahi[arow * 8 + ((4 + kg) ^ sw)];
            bf16x8 a1l = Alo[arow * 8 + ((4 + kg) ^ sw)];
            f32x4 acc0 = zero4, acc1 = zero4;
            MFMA6(acc0, a0h, a0l, a1h, a1l, bh[0][0], bl[0][0], bh[0][1], bl[0][1])
            MFMA6(acc1, a0h, a0l, a1h, a1l, bh[1][0], bl[1][0], bh[1][1], bl[1][1])
            #pragma unroll
            for (int r = 0; r < 4; r++) {
                int row = m0 + m * 16 + kg * 4 + r;
                int gid = blockIdx.x * ROWS + row;
                int env = gid / E2;
                int e   = gid - env * E2;
                int src = edges[e];                // src is edges[e] for BOTH directions
                float* sp = store + ((size_t)env * NNODES + src) * EFEAT;
                atomicAdd(sp + lr, acc0[r] + bb0);
                if (lr < 4) atomicAdd(sp + 16 + lr, acc1[r] + bb1);
            }
        }
    }
#undef MFMA6
}

// One thread per (env, node): GRU single step, in-place on nf (f32).
__global__ __launch_bounds__(256) void gru_kernel(
    const float* __restrict__ store,
    const float* __restrict__ Wih, const float* __restrict__ bih,
    const float* __restrict__ Whh, const float* __restrict__ bhh,
    float* __restrict__ nf)
{
    int gid = blockIdx.x * blockDim.x + threadIdx.x;
    const int total = NENV * NNODES;
    if (gid >= total) return;

    const float* s = store + (size_t)gid * EFEAT;
    float*       h = nf    + (size_t)gid * NFEAT;

    float sv[EFEAT], hv[NFEAT];
    #pragma unroll
    for (int k = 0; k < EFEAT; k++) sv[k] = s[k];
    #pragma unroll
    for (int k = 0; k < NFEAT; k++) hv[k] = h[k];

    for (int t = 0; t < NFEAT; t++) {
        float ir = bih[t],            hr = bhh[t];
        float iz = bih[NFEAT + t],    hz = bhh[NFEAT + t];
        float in_ = bih[2*NFEAT + t], hn = bhh[2*NFEAT + t];
        const float* wr = Wih + t * EFEAT;
        const float* wz = Wih + (NFEAT + t) * EFEAT;
        const float* wn = Wih + (2*NFEAT + t) * EFEAT;
        #pragma unroll
        for (int k = 0; k < EFEAT; k++) {
            ir  = fmaf(sv[k], wr[k], ir);
            iz  = fmaf(sv[k], wz[k], iz);
            in_ = fmaf(sv[k], wn[k], in_);
        }
        const float* vr = Whh + t * NFEAT;
        const float* vz = Whh + (NFEAT + t) * NFEAT;
        const float* vn = Whh + (2*NFEAT + t) * NFEAT;
        #pragma unroll
        for (int k = 0; k < NFEAT; k++) {
            hr = fmaf(hv[k], vr[k], hr);
            hz = fmaf(hv[k], vz[k], hz);
            hn = fmaf(hv[k], vn[k], hn);
        }
        float r = fast_sigmoid(ir + hr);
        float z = fast_sigmoid(iz + hz);
        float n = fast_tanh(in_ + r * hn);
        h[t] = (1.f - z) * n + z * hv[t];
    }
}

extern "C" void kernel_launch(void* const* d_in, const int* in_sizes, int n_in,
                              void* d_out, int out_size, void* d_ws, size_t ws_size,
                              hipStream_t stream) {
    const float* nf_in = (const float*)d_in[0];
    const int*   edges = (const int*)d_in[1];
    const float* W1 = (const float*)d_in[2];
    const float* b1 = (const float*)d_in[3];
    const float* W2 = (const float*)d_in[4];
    const float* b2 = (const float*)d_in[5];
    const float* W3 = (const float*)d_in[6];
    const float* b3 = (const float*)d_in[7];
    const float* Wih = (const float*)d_in[8];
    const float* Whh = (const float*)d_in[9];
    const float* bih = (const float*)d_in[10];
    const float* bhh = (const float*)d_in[11];

    float* nf    = (float*)d_out;
    float* store = (float*)d_ws;
    const size_t nf_bytes    = (size_t)NENV * NNODES * NFEAT * sizeof(float);
    const size_t store_bytes = (size_t)NENV * NNODES * EFEAT * sizeof(float);
    ushort* W1h = (ushort*)((char*)d_ws + store_bytes);
    ushort* W1l = W1h + 64 * 64;
    ushort* W2h = W1l + 64 * 64;
    ushort* W2l = W2h + 64 * 64;
    ushort* W3h = W2l + 64 * 64;
    ushort* W3l = W3h + 32 * 64;

    prep_weights<<<1, 256, 0, stream>>>(W1, W2, W3, W1h, W1l, W2h, W2l, W3h, W3l);
    hipMemcpyAsync(nf, nf_in, nf_bytes, hipMemcpyDeviceToDevice, stream);

    const int edge_blocks = (NENV * E2) / ROWS;           // 12500, exact
    const int node_total  = NENV * NNODES;
    dim3 grid_n((node_total + 255) / 256);

    for (int it = 0; it < ITERS; it++) {
        hipMemsetAsync(store, 0, store_bytes, stream);
        edge_mlp_mfma<<<edge_blocks, ROWS, 0, stream>>>(nf, edges,
                                                        W1h, W1l, W2h, W2l, W3h, W3l,
                                                        b1, b2, b3, store);
        gru_kernel<<<grid_n, 256, 0, stream>>>(store, Wih, bih, Whh, bhh, nf);
    }
}